// Round 4
// baseline (444.973 us; speedup 1.0000x reference)
//
#include <hip/hip_runtime.h>
#include <stdint.h>

// ---------- bf16 helpers (storage = unsigned short) ----------
__device__ __forceinline__ float b2f(unsigned short u) {
    union { uint32_t i; float f; } v; v.i = ((uint32_t)u) << 16; return v.f;
}
__device__ __forceinline__ unsigned short f2b(float f) {
    union { float f; uint32_t i; } v; v.f = f;
    uint32_t r = v.i + 0x7fffu + ((v.i >> 16) & 1u);   // RNE
    return (unsigned short)(r >> 16);
}

typedef __bf16 bf16x8 __attribute__((ext_vector_type(8)));
typedef float  f32x16 __attribute__((ext_vector_type(16)));

// ---------------------------------------------------------------------------
// cvt: xb = bf16(x), 8 elems/thread.
// ---------------------------------------------------------------------------
__global__ __launch_bounds__(256)
void cvt_f32_bf16(const float* __restrict__ x, unsigned short* __restrict__ xb) {
    int t = blockIdx.x * 256 + threadIdx.x;
    const float4* p = (const float4*)(x + (size_t)t * 8);
    float4 f0 = p[0], f1 = p[1];
    int4 o;
    o.x = (uint32_t)f2b(f0.x) | ((uint32_t)f2b(f0.y) << 16);
    o.y = (uint32_t)f2b(f0.z) | ((uint32_t)f2b(f0.w) << 16);
    o.z = (uint32_t)f2b(f1.x) | ((uint32_t)f2b(f1.y) << 16);
    o.w = (uint32_t)f2b(f1.z) | ((uint32_t)f2b(f1.w) << 16);
    ((int4*)xb)[t] = o;
}

// ---------------------------------------------------------------------------
// bias_fill: out[r][c] = bias[c]  (f32, 1024 cols = 256 float4 per row)
// ---------------------------------------------------------------------------
__global__ __launch_bounds__(256)
void bias_fill(const float* __restrict__ b, float4* __restrict__ out) {
    int t = blockIdx.x * 256 + threadIdx.x;
    out[t] = ((const float4*)b)[t & 255];
}

// ---------------------------------------------------------------------------
// build_T: T[rm=(r1*16+n2)*16+m2][n3][m3] = sum_r2 c1[rm][r2]*c2[(r2*N3+n3)*M3+m3]
// Size: 4096 * N3 * M3 = 524288 elems -> 2048 blocks x 256 (DO NOT SHRINK:
// R3 regression used 128 blocks and computed 1/16 of T -> absmax 3.5).
// ---------------------------------------------------------------------------
template<int N3, int M3>
__global__ void build_T(const float* __restrict__ c1,
                        const float* __restrict__ c2,
                        float* __restrict__ T) {
    int e = blockIdx.x * 256 + threadIdx.x;
    int m3 = e % M3;
    int t  = e / M3;
    int n3 = t % N3;
    int rm = t / N3;
    float s = 0.f;
#pragma unroll
    for (int r2 = 0; r2 < 16; ++r2)
        s += c1[rm * 16 + r2] * c2[(r2 * N3 + n3) * M3 + m3];
    T[e] = s;
}

// ---------------------------------------------------------------------------
// build_W (coalesced remap): thread t = (((n1*M1+m1)*N2+n2)*M2+m2)*M3+m3.
// ---------------------------------------------------------------------------
template<int N1, int N2, int N3, int M1, int M2, int M3>
__global__ __launch_bounds__(256)
void build_W(const float* __restrict__ c0,
             const float* __restrict__ T,
             unsigned short* __restrict__ W) {
    constexpr int K = N1 * N2 * N3;
    int t  = blockIdx.x * 256 + threadIdx.x;
    int m3 = t % M3;
    int m2 = (t / M3) % M2;
    int n2 = (t / (M3 * M2)) % N2;
    int m1 = (t / (M3 * M2 * N2)) % M1;
    int n1 =  t / (M3 * M2 * N2 * M1);

    float c0r[16];
    const float4* c0p = (const float4*)(c0 + (n1 * M1 + m1) * 16);
#pragma unroll
    for (int i = 0; i < 4; ++i) ((float4*)c0r)[i] = c0p[i];

    float acc[N3] = {};
#pragma unroll
    for (int r1 = 0; r1 < 16; ++r1) {
        const float* Tp = T + (size_t)(((r1 * 16 + n2) * 16 + m2) * N3) * M3 + m3;
#pragma unroll
        for (int n3 = 0; n3 < N3; ++n3)
            acc[n3] += c0r[r1] * Tp[n3 * M3];
    }

    unsigned short ob[N3];
#pragma unroll
    for (int n3 = 0; n3 < N3; ++n3) ob[n3] = f2b(acc[n3]);

    unsigned short* dst = W + (size_t)((m1 * M2 + m2) * M3 + m3) * K
                            + (n1 * N2 + n2) * N3;
#pragma unroll
    for (int c = 0; c < N3 / 8; ++c)
        ((int4*)dst)[c] = ((const int4*)ob)[c];
}

// ---------------------------------------------------------------------------
// gemm_pc2: producer-consumer GEMM with ONE-ITERATION LOAD->STORE SLACK.
//
// C[M][NCOLS] = A[M][K]*Bt[NCOLS][K]^T (+bias, opt GELU)  or  atomic +=.
// Block tile BM=256 x BN=128, BK=64.  512 threads:
//   waves 0-3 CONSUME: 2x2 wave grid, 128x64 each (FI=4 x FJ=2 in 32x32x16
//   MFMA units, acc = 128 VGPR).
//   waves 4-7 PRODUCE: global->reg->LDS, double-buffered LDS (2 x 48KB),
//   DOUBLE-DEEP register pipeline: at iter t they issue loads for tile t+2
//   and then store tile t+1 (loaded one full iteration earlier).  The
//   store's register dependency makes the compiler emit a COUNTED vmcnt
//   (t+2's 12 loads stay in flight), so ~1.5 tile-times of HBM latency are
//   covered.  R0's zero-slack version (load t+1, store t+1 same iter)
//   exposed the full gather latency at every barrier -> 1.8k cy/tile bubble.
//
// Consumers never touch vmcnt.  Plain __syncthreads throughout (barrier
// counts match: producers 1+NT, consumers 1+NT).
//
// LDS swizzle (R0-proven, 0 measured conflicts): store chunk slot
// jg = jj ^ lr ^ (c&7); i.e. LDS[r][s] holds global chunk s ^ key(r),
// key(r) = (r&7) ^ ((r>>3)&7).  Read slot = (ks*2+khalf) ^ key(r).
// C/D mapping (m74/m101): col=lane&31, row=(reg&3)+8*(reg>>2)+4*(lane>>5).
// ---------------------------------------------------------------------------
template<int BM, int BN, int KCH, int NCOLS, int GX, int GY,
         bool DO_GELU, bool ATOMIC>
__global__ __launch_bounds__(512, 2)
void gemm_pc2(const unsigned short* __restrict__ A,
              const unsigned short* __restrict__ Bt,
              const float* __restrict__ bias,
              void* __restrict__ Cv,
              int kstride)
{
    constexpr int BK  = 64;
    constexpr int NT  = KCH / BK;            // even (16 or 32)
    constexpr int CA  = BM / 8, CB = BN / 8; // 8-row chunks per tile
    constexpr int PA  = CA / 4, PB = CB / 4; // chunks per producer wave
    constexpr int ASZ = BM * BK, BSZ = BN * BK;   // elems
    constexpr int BUFE = ASZ + BSZ;               // elems per LDS buffer

    extern __shared__ unsigned short sh[];   // [2][BUFE]

    const int tid   = threadIdx.x;
    const int lane  = tid & 63;
    const int wave  = tid >> 6;
    const int lr    = lane >> 3;
    const int jj    = lane & 7;
    const int m32   = lane & 31;
    const int khalf = lane >> 5;

    // XCD-chunked bijective block swizzle (total % 8 == 0 for our grids)
    int lin = ((int)blockIdx.z * GY + (int)blockIdx.y) * GX + (int)blockIdx.x;
    const int total = GX * GY * (int)gridDim.z;
    const int cpx = total >> 3;
    lin = (lin & 7) * cpx + (lin >> 3);
    const int colT = lin % GX;
    const int rowT = (lin / GX) % GY;
    const int kz   = lin / (GX * GY);
    const int rowBase = rowT * BM;
    const int colBase = colT * BN;
    const int kOff    = kz * KCH;

    if (wave >= 4) {
        // ================= PRODUCER =================
        const int pw = wave - 4;
        int4 rA0[PA], rB0[PB];   // even tiles
        int4 rA1[PA], rB1[PB];   // odd tiles

        auto LOADP = [&](int4 (&aR)[PA], int4 (&bR)[PB], int t) {
            const int kk = kOff + t * BK;
#pragma unroll
            for (int it = 0; it < PA; ++it) {
                const int c  = pw * PA + it;
                const int jg = jj ^ lr ^ (c & 7);
                aR[it] = *(const int4*)(A +
                    (size_t)(rowBase + c * 8 + lr) * kstride + kk + jg * 8);
            }
#pragma unroll
            for (int it = 0; it < PB; ++it) {
                const int c  = pw * PB + it;
                const int jg = jj ^ lr ^ (c & 7);
                bR[it] = *(const int4*)(Bt +
                    (size_t)(colBase + c * 8 + lr) * kstride + kk + jg * 8);
            }
        };
        auto STOREP = [&](int4 (&aR)[PA], int4 (&bR)[PB], int b) {
            unsigned short* As = sh + b * BUFE;
            unsigned short* Bs = As + ASZ;
#pragma unroll
            for (int it = 0; it < PA; ++it)
                *(int4*)&As[(pw * PA + it) * 512 + lane * 8] = aR[it];
#pragma unroll
            for (int it = 0; it < PB; ++it)
                *(int4*)&Bs[(pw * PB + it) * 512 + lane * 8] = bR[it];
        };

        // prologue: tiles 0,1 in regs; store 0
        LOADP(rA0, rB0, 0);
        LOADP(rA1, rB1, 1);
        STOREP(rA0, rB0, 0);
        __syncthreads();

        for (int t = 0; t < NT; t += 2) {
            // even iter t: consumers read buf0(tile t)
            if (t + 2 < NT) LOADP(rA0, rB0, t + 2);   // issue ahead
            STOREP(rA1, rB1, 1);                      // tile t+1 -> buf1
            __syncthreads();
            // odd iter t+1: consumers read buf1(tile t+1)
            if (t + 3 < NT) LOADP(rA1, rB1, t + 3);
            if (t + 2 < NT) STOREP(rA0, rB0, 0);      // tile t+2 -> buf0
            __syncthreads();
        }
    } else {
        // ================= CONSUMER =================
        const int wm = wave >> 1, wn = wave & 1;
        const int waveM = wm * 128, waveN = wn * 64;
        f32x16 acc[4][2] = {};

        int aAddr[4], aKey[4], bAddr[2], bKey[2];
#pragma unroll
        for (int i = 0; i < 4; ++i) {
            const int r = waveM + i * 32 + m32;
            aAddr[i] = r * BK;
            aKey[i]  = (r & 7) ^ ((r >> 3) & 7);
        }
#pragma unroll
        for (int j = 0; j < 2; ++j) {
            const int r = waveN + j * 32 + m32;
            bAddr[j] = ASZ + r * BK;
            bKey[j]  = (r & 7) ^ ((r >> 3) & 7);
        }

        __syncthreads();                 // tile 0 staged

        for (int t = 0; t < NT; ++t) {
            const unsigned short* base = sh + (t & 1) * BUFE;
#pragma unroll
            for (int ks = 0; ks < 4; ++ks) {
                bf16x8 a_f[4], b_f[2];
                const int g = ks * 2 + khalf;
#pragma unroll
                for (int i = 0; i < 4; ++i)
                    a_f[i] = *(const bf16x8*)&base[aAddr[i] + (g ^ aKey[i]) * 8];
#pragma unroll
                for (int j = 0; j < 2; ++j)
                    b_f[j] = *(const bf16x8*)&base[bAddr[j] + (g ^ bKey[j]) * 8];
#pragma unroll
                for (int i = 0; i < 4; ++i)
#pragma unroll
                    for (int j = 0; j < 2; ++j)
                        acc[i][j] = __builtin_amdgcn_mfma_f32_32x32x16_bf16(
                            a_f[i], b_f[j], acc[i][j], 0, 0, 0);
            }
            __syncthreads();
        }

        // epilogue: col=lane&31, row=(reg&3)+8*(reg>>2)+4*(lane>>5)
#pragma unroll
        for (int i = 0; i < 4; ++i) {
#pragma unroll
            for (int j = 0; j < 2; ++j) {
                const int col = colBase + waveN + j * 32 + m32;
                const float bv = ATOMIC ? 0.f : bias[col];
#pragma unroll
                for (int reg = 0; reg < 16; ++reg) {
                    const int row = rowBase + waveM + i * 32 +
                                    (reg & 3) + 8 * (reg >> 2) + 4 * khalf;
                    const size_t off = (size_t)row * NCOLS + col;
                    if (ATOMIC) {
                        unsafeAtomicAdd((float*)Cv + off, acc[i][j][reg]);
                    } else {
                        float z = acc[i][j][reg] + bv;
                        if (DO_GELU)
                            z = 0.5f * z * (1.f + erff(z * 0.70710678118654752f));
                        ((unsigned short*)Cv)[off] = f2b(z);
                    }
                }
            }
        }
    }
}

// ---------------------------------------------------------------------------
// OLD producer-consumer GEMM -- kept ONLY for the small-workspace fallback.
// ---------------------------------------------------------------------------
#define PC_COMPUTE(BUF)                                                       \
    {                                                                         \
        _Pragma("unroll")                                                     \
        for (int ks = 0; ks < 4; ++ks) {                                      \
            bf16x8 a_f[FI], b_f[FJ];                                          \
            _Pragma("unroll")                                                 \
            for (int i = 0; i < FI; ++i) {                                    \
                const int key = (m32 & 7) ^                                   \
                    (((waveM >> 3) + 4 * i + (m32 >> 3)) & 7);                \
                const int slot = ((ks * 2 + khalf) ^ key) * 8;                \
                a_f[i] = *(const bf16x8*)&As[(BUF) * ASZ +                    \
                          (waveM + i * 32 + m32) * BK + slot];                \
            }                                                                 \
            _Pragma("unroll")                                                 \
            for (int j = 0; j < FJ; ++j) {                                    \
                const int key = (m32 & 7) ^                                   \
                    (((waveN >> 3) + 4 * j + (m32 >> 3)) & 7);                \
                const int slot = ((ks * 2 + khalf) ^ key) * 8;                \
                b_f[j] = *(const bf16x8*)&Bs[(BUF) * BSZ +                    \
                          (waveN + j * 32 + m32) * BK + slot];                \
            }                                                                 \
            _Pragma("unroll")                                                 \
            for (int i = 0; i < FI; ++i)                                      \
                _Pragma("unroll")                                             \
                for (int j = 0; j < FJ; ++j)                                  \
                    acc[i][j] = __builtin_amdgcn_mfma_f32_32x32x16_bf16(      \
                        a_f[i], b_f[j], acc[i][j], 0, 0, 0);                  \
        }                                                                     \
    }

template<int BM, int BN, int KTOT, bool DO_GELU, bool A_F32, bool C_F32>
__global__ __launch_bounds__(512, 4)
void gemm_pc(const void* __restrict__ Av,
             const unsigned short* __restrict__ Bt,
             const float* __restrict__ bias,
             void* __restrict__ Cv,
             int Ncols) {
    constexpr int BK  = 64;
    constexpr int CA  = BM / 8;
    constexpr int CB  = BN / 8;
    constexpr int PA  = CA / 4;
    constexpr int PB  = CB / 4;
    constexpr int FI  = BM / 64;
    constexpr int FJ  = BN / 64;
    constexpr int ASZ = BM * BK;
    constexpr int BSZ = BN * BK;
    __shared__ unsigned short As[2 * ASZ];
    __shared__ unsigned short Bs[2 * BSZ];

    const int tid  = threadIdx.x;
    const int lane = tid & 63;
    const int wave = tid >> 6;
    const int rowBase = blockIdx.y * BM;
    const int colBase = blockIdx.x * BN;

    const int lr    = lane >> 3;
    const int jj    = lane & 7;
    const int m32   = lane & 31;
    const int khalf = lane >> 5;

    if (wave >= 4) {
        const int pw = wave - 4;
#pragma unroll
        for (int it = 0; it < PA; ++it) {
            const int c  = pw * PA + it;
            const int jg = jj ^ lr ^ (c & 7);
            const size_t aoff = (size_t)(rowBase + c * 8 + lr) * KTOT + jg * 8;
            int4 v;
            if (A_F32) {
                const float* ga = (const float*)Av + aoff;
                float4 f0 = *(const float4*)ga;
                float4 f1 = *(const float4*)(ga + 4);
                v.x = (uint32_t)f2b(f0.x) | ((uint32_t)f2b(f0.y) << 16);
                v.y = (uint32_t)f2b(f0.z) | ((uint32_t)f2b(f0.w) << 16);
                v.z = (uint32_t)f2b(f1.x) | ((uint32_t)f2b(f1.y) << 16);
                v.w = (uint32_t)f2b(f1.z) | ((uint32_t)f2b(f1.w) << 16);
            } else {
                v = *(const int4*)((const unsigned short*)Av + aoff);
            }
            *(int4*)&As[c * 512 + lane * 8] = v;
        }
#pragma unroll
        for (int it = 0; it < PB; ++it) {
            const int c  = pw * PB + it;
            const int jg = jj ^ lr ^ (c & 7);
            *(int4*)&Bs[c * 512 + lane * 8] =
                *(const int4*)(Bt + (size_t)(colBase + c * 8 + lr) * KTOT + jg * 8);
        }
        __syncthreads();

        int buf = 1;
        for (int k0 = BK; k0 < KTOT; k0 += BK) {
            int4 aR[PA], bR[PB];
#pragma unroll
            for (int it = 0; it < PA; ++it) {
                const int c  = pw * PA + it;
                const int jg = jj ^ lr ^ (c & 7);
                const size_t aoff = (size_t)(rowBase + c * 8 + lr) * KTOT + k0 + jg * 8;
                if (A_F32) {
                    const float* ga = (const float*)Av + aoff;
                    float4 f0 = *(const float4*)ga;
                    float4 f1 = *(const float4*)(ga + 4);
                    int4 v;
                    v.x = (uint32_t)f2b(f0.x) | ((uint32_t)f2b(f0.y) << 16);
                    v.y = (uint32_t)f2b(f0.z) | ((uint32_t)f2b(f0.w) << 16);
                    v.z = (uint32_t)f2b(f1.x) | ((uint32_t)f2b(f1.y) << 16);
                    v.w = (uint32_t)f2b(f1.z) | ((uint32_t)f2b(f1.w) << 16);
                    aR[it] = v;
                } else {
                    aR[it] = *(const int4*)((const unsigned short*)Av + aoff);
                }
            }
#pragma unroll
            for (int it = 0; it < PB; ++it) {
                const int c  = pw * PB + it;
                const int jg = jj ^ lr ^ (c & 7);
                bR[it] = *(const int4*)(Bt + (size_t)(colBase + c * 8 + lr) * KTOT + k0 + jg * 8);
            }
#pragma unroll
            for (int it = 0; it < PA; ++it) {
                const int c = pw * PA + it;
                *(int4*)&As[buf * ASZ + c * 512 + lane * 8] = aR[it];
            }
#pragma unroll
            for (int it = 0; it < PB; ++it) {
                const int c = pw * PB + it;
                *(int4*)&Bs[buf * BSZ + c * 512 + lane * 8] = bR[it];
            }
            __syncthreads();
            buf ^= 1;
        }
    } else {
        const int waveM = (wave >> 1) * (BM / 2);
        const int waveN = (wave & 1) * (BN / 2);
        f32x16 acc[FI][FJ] = {};

        __syncthreads();

        int cur = 0;
        for (int k0 = BK; k0 < KTOT; k0 += BK) {
            PC_COMPUTE(cur)
            __syncthreads();
            cur ^= 1;
        }
        PC_COMPUTE(cur)

#pragma unroll
        for (int i = 0; i < FI; ++i) {
#pragma unroll
            for (int j = 0; j < FJ; ++j) {
                const int col = colBase + waveN + j * 32 + m32;
                const float bv = bias[col];
#pragma unroll
                for (int reg = 0; reg < 16; ++reg) {
                    const int row = rowBase + waveM + i * 32 +
                                    (reg & 3) + 8 * (reg >> 2) + 4 * khalf;
                    float z = acc[i][j][reg] + bv;
                    if (DO_GELU)
                        z = 0.5f * z * (1.f + erff(z * 0.70710678118654752f));
                    const size_t off = (size_t)row * Ncols + col;
                    if (C_F32) ((float*)Cv)[off] = z;
                    else       ((unsigned short*)Cv)[off] = f2b(z);
                }
            }
        }
    }
}

// ---------------------------------------------------------------------------
extern "C" void kernel_launch(void* const* d_in, const int* in_sizes, int n_in,
                              void* d_out, int out_size, void* d_ws, size_t ws_size,
                              hipStream_t stream) {
    const float* x      = (const float*)d_in[0];   // [4096,1024] fp32
    const float* fc1_c0 = (const float*)d_in[1];
    const float* fc1_c1 = (const float*)d_in[2];
    const float* fc1_c2 = (const float*)d_in[3];
    const float* fc1_b  = (const float*)d_in[4];
    const float* fc2_c0 = (const float*)d_in[5];
    const float* fc2_c1 = (const float*)d_in[6];
    const float* fc2_c2 = (const float*)d_in[7];
    const float* fc2_b  = (const float*)d_in[8];

    // Workspace layout (50 MB preferred):
    //   [0,8M)   W    bf16 -- W1t [4096][1024], later W2t [1024][4096]
    //   [8,10M)  T    f32 scratch (524288 floats = 2 MB exactly)
    //   [10,18M) xb   bf16 copy of x
    //   [18,50M) h    bf16 [4096][4096]
    char* ws = (char*)d_ws;
    unsigned short* W  = (unsigned short*)(ws);
    float*          T  = (float*)(ws + (8u << 20));
    const bool big = ws_size >= (50ull << 20);
    unsigned short* xb = (unsigned short*)(ws + (10u << 20));
    unsigned short* h  = (unsigned short*)(ws + (big ? (18u << 20) : (10u << 20)));

    constexpr int DLDS = 2 * (256 + 128) * 64 * 2;   // 96 KB double-buffer

    // Dynamic-LDS opt-in (>64KB).  Non-stream metadata call: graph-capture safe.
    static bool attr_done = false;
    if (!attr_done) {
        attr_done = true;
        (void)hipFuncSetAttribute(
            reinterpret_cast<const void*>(
                &gemm_pc2<256, 128, 1024, 4096, 32, 16, true, false>),
            hipFuncAttributeMaxDynamicSharedMemorySize, DLDS);
        (void)hipFuncSetAttribute(
            reinterpret_cast<const void*>(
                &gemm_pc2<256, 128, 2048, 1024, 8, 16, false, true>),
            hipFuncAttributeMaxDynamicSharedMemorySize, DLDS);
    }

    // ---- layer 1: in (8,16,8) -> out (16,16,16)
    build_T<8, 16><<<2048, 256, 0, stream>>>(fc1_c1, fc1_c2, T);
    build_W<8, 16, 8, 16, 16, 16><<<2048, 256, 0, stream>>>(fc1_c0, T, W);
    if (big) {
        cvt_f32_bf16<<<2048, 256, 0, stream>>>(x, xb);
        // GEMM1: 256x128 tile, grid 32x16 = 512 blocks, 96KB LDS
        gemm_pc2<256, 128, 1024, 4096, 32, 16, true, false>
            <<<dim3(32, 16, 1), 512, DLDS, stream>>>(xb, W, fc1_b, h, 1024);
    } else {
        gemm_pc<128, 128, 1024, true, true, false>
            <<<dim3(32, 32), 512, 0, stream>>>(x, W, fc1_b, h, 4096);
    }

    // ---- layer 2: in (16,16,16) -> out (8,16,8)
    build_T<16, 8><<<2048, 256, 0, stream>>>(fc2_c1, fc2_c2, T);
    build_W<16, 16, 16, 8, 16, 8><<<1024, 256, 0, stream>>>(fc2_c0, T, W);
    if (big) {
        // prefill output with bias, then K-split=2 atomic-add GEMM
        bias_fill<<<4096, 256, 0, stream>>>(fc2_b, (float4*)d_out);
        // GEMM2: 256x128 tile, K-split 2, grid 8x16x2 = 256 blocks
        gemm_pc2<256, 128, 2048, 1024, 8, 16, false, true>
            <<<dim3(8, 16, 2), 512, DLDS, stream>>>(h, W, fc2_b, d_out, 4096);
    } else {
        gemm_pc<128, 64, 4096, false, false, true>
            <<<dim3(16, 32), 512, 0, stream>>>(h, W, fc2_b, d_out, 1024);
    }
}

// Round 5
// 301.880 us; speedup vs baseline: 1.4740x; 1.4740x over previous
//
#include <hip/hip_runtime.h>
#include <stdint.h>

// ---------- bf16 helpers (storage = unsigned short) ----------
__device__ __forceinline__ float b2f(unsigned short u) {
    union { uint32_t i; float f; } v; v.i = ((uint32_t)u) << 16; return v.f;
}
__device__ __forceinline__ unsigned short f2b(float f) {
    union { float f; uint32_t i; } v; v.f = f;
    uint32_t r = v.i + 0x7fffu + ((v.i >> 16) & 1u);   // RNE
    return (unsigned short)(r >> 16);
}

typedef __bf16 bf16x8 __attribute__((ext_vector_type(8)));
typedef float  f32x16 __attribute__((ext_vector_type(16)));

// ---------------------------------------------------------------------------
// build_T (device body): T[rm=(r1*16+n2)*16+m2][n3][m3]
//   = sum_r2 c1[rm][r2] * c2[(r2*N3+n3)*M3+m3]
// 524288 elems per layer -> 2048 blocks x 256 each.
// ---------------------------------------------------------------------------
template<int N3, int M3>
__device__ __forceinline__ void build_T_body(int e,
                                             const float* __restrict__ c1,
                                             const float* __restrict__ c2,
                                             float* __restrict__ T) {
    int m3 = e % M3;
    int t  = e / M3;
    int n3 = t % N3;
    int rm = t / N3;
    float s = 0.f;
#pragma unroll
    for (int r2 = 0; r2 < 16; ++r2)
        s += c1[rm * 16 + r2] * c2[(r2 * N3 + n3) * M3 + m3];
    T[e] = s;
}

// Fused: blocks [0,2048) -> layer-1 T, [2048,4096) -> layer-2 T.
__global__ __launch_bounds__(256)
void build_T_both(const float* __restrict__ c11, const float* __restrict__ c12,
                  float* __restrict__ T1,
                  const float* __restrict__ c21, const float* __restrict__ c22,
                  float* __restrict__ T2) {
    const int b = blockIdx.x;
    if (b < 2048) build_T_body<8, 16>(b * 256 + threadIdx.x, c11, c12, T1);
    else          build_T_body<16, 8>((b - 2048) * 256 + threadIdx.x, c21, c22, T2);
}

// ---------------------------------------------------------------------------
// build_W (device body): thread t = (((n1*M1+m1)*N2+n2)*M2+m2)*M3+m3.
// W[outRow = (m1*M2+m2)*M3+m3][K] (B^T layout, bf16), K = N1*N2*N3.
// ---------------------------------------------------------------------------
template<int N1, int N2, int N3, int M1, int M2, int M3>
__device__ __forceinline__ void build_W_body(int t,
                                             const float* __restrict__ c0,
                                             const float* __restrict__ T,
                                             unsigned short* __restrict__ W) {
    constexpr int K = N1 * N2 * N3;
    int m3 = t % M3;
    int m2 = (t / M3) % M2;
    int n2 = (t / (M3 * M2)) % N2;
    int m1 = (t / (M3 * M2 * N2)) % M1;
    int n1 =  t / (M3 * M2 * N2 * M1);

    float c0r[16];
    const float4* c0p = (const float4*)(c0 + (n1 * M1 + m1) * 16);
#pragma unroll
    for (int i = 0; i < 4; ++i) ((float4*)c0r)[i] = c0p[i];

    float acc[N3] = {};
#pragma unroll
    for (int r1 = 0; r1 < 16; ++r1) {
        const float* Tp = T + (size_t)(((r1 * 16 + n2) * 16 + m2) * N3) * M3 + m3;
#pragma unroll
        for (int n3 = 0; n3 < N3; ++n3)
            acc[n3] += c0r[r1] * Tp[n3 * M3];
    }

    unsigned short ob[N3];
#pragma unroll
    for (int n3 = 0; n3 < N3; ++n3) ob[n3] = f2b(acc[n3]);

    unsigned short* dst = W + (size_t)((m1 * M2 + m2) * M3 + m3) * K
                            + (n1 * N2 + n2) * N3;
#pragma unroll
    for (int c = 0; c < N3 / 8; ++c)
        ((int4*)dst)[c] = ((const int4*)ob)[c];
}

// Fused: blocks [0,2048) -> W1 (524288 thr), [2048,3072) -> W2 (262144 thr).
__global__ __launch_bounds__(256)
void build_W_both(const float* __restrict__ c10, const float* __restrict__ T1,
                  unsigned short* __restrict__ W1,
                  const float* __restrict__ c20, const float* __restrict__ T2,
                  unsigned short* __restrict__ W2) {
    const int b = blockIdx.x;
    if (b < 2048)
        build_W_body<8, 16, 8, 16, 16, 16>(b * 256 + threadIdx.x, c10, T1, W1);
    else
        build_W_body<16, 16, 16, 8, 16, 8>((b - 2048) * 256 + threadIdx.x, c20, T2, W2);
}

// Standalone single-layer build_W (small-workspace fallback path only).
template<int N1, int N2, int N3, int M1, int M2, int M3>
__global__ __launch_bounds__(256)
void build_W(const float* __restrict__ c0, const float* __restrict__ T,
             unsigned short* __restrict__ W) {
    build_W_body<N1, N2, N3, M1, M2, M3>(blockIdx.x * 256 + threadIdx.x, c0, T, W);
}

// ---------------------------------------------------------------------------
// gemm_pc3: R0's proven producer-consumer GEMM + ROTATED producer loop.
//
// C[M][Ncols] = A[M][K] * Bt[Ncols][K]^T + bias (opt GELU).
// Block tile BM x BN, BK=64, 512 threads:
//   waves 0-3 CONSUME (2x2 wave grid, (BM/2)x(BN/2) each, 32x32x16 MFMA).
//   waves 4-7 PRODUCE (global->reg->LDS, double-buffered LDS).
//
// ROTATION (the one structural change vs the 62us R0 kernel): producer
// iteration t does  STORE(tile t+1, regs loaded LAST iter)  then
// LOAD(tile t+2) then barrier.  The ds_write's register dependency forces
// a counted wait on loads that have had one full tile-phase in flight, so
// load latency is covered -- R0's load-then-store exposed it all.  Register
// footprint is IDENTICAL to R0 (ONE tile set; R4's two-set version spilled:
// WRITE_SIZE 418MB vs 33MB ideal).  No lambdas, no arrays-by-reference.
//
// Barrier ledger: producer 1 + NT, consumer 1 + NT.  Tile t is stored
// before barrier #t; consumer reads it after barrier #t.  Store target
// buf (t+1)&1 is disjoint from consumer's read buf t&1.
//
// A_F32: producer loads A as float4 pairs, converts (f2b) at STORE time so
// the raw loads stay in flight across the slack window.
//
// LDS swizzle (R0-proven, 0 conflicts): lane jj stores global chunk
// jj^key(r) at slot jj, key(r) = (r&7)^((r>>3)&7); read slot = g^key(r).
// C/D mapping (m74/m101): col=lane&31, row=(reg&3)+8*(reg>>2)+4*(lane>>5).
// ---------------------------------------------------------------------------
template<int BM, int BN, int KTOT, bool DO_GELU, bool A_F32, bool C_F32>
__global__ __launch_bounds__(512, 4)
void gemm_pc3(const void* __restrict__ Av,
              const unsigned short* __restrict__ Bt,
              const float* __restrict__ bias,
              void* __restrict__ Cv,
              int Ncols)
{
    constexpr int BK  = 64;
    constexpr int NT  = KTOT / BK;
    constexpr int CA  = BM / 8, CB = BN / 8;   // 8-row chunks per tile
    constexpr int PA  = CA / 4, PB = CB / 4;   // chunks per producer wave
    constexpr int FI  = BM / 64, FJ = BN / 64;
    constexpr int ASZ = BM * BK, BSZ = BN * BK;
    __shared__ unsigned short As[2 * ASZ];
    __shared__ unsigned short Bs[2 * BSZ];

    const int tid   = threadIdx.x;
    const int lane  = tid & 63;
    const int wave  = tid >> 6;
    const int lr    = lane >> 3;
    const int jj    = lane & 7;
    const int m32   = lane & 31;
    const int khalf = lane >> 5;
    const int rowBase = blockIdx.y * BM;
    const int colBase = blockIdx.x * BN;

    if (wave >= 4) {
        // ================= PRODUCER =================
        const int pw = wave - 4;
        float4 aF[PA][2];   // raw f32 A (A_F32 path)      -- one tile only
        int4   aR[PA];      // packed bf16 A (bf16 path)   -- one tile only
        int4   bR[PB];

#define PC3_LOAD(T_)                                                          \
        { const int kk = (T_) * BK;                                           \
          _Pragma("unroll")                                                   \
          for (int it = 0; it < PA; ++it) {                                   \
              const int c  = pw * PA + it;                                    \
              const int jg = jj ^ lr ^ (c & 7);                               \
              const size_t aoff = (size_t)(rowBase + c * 8 + lr) * KTOT       \
                                  + kk + jg * 8;                              \
              if constexpr (A_F32) {                                          \
                  const float* ga = (const float*)Av + aoff;                  \
                  aF[it][0] = *(const float4*)ga;                             \
                  aF[it][1] = *(const float4*)(ga + 4);                       \
              } else {                                                        \
                  aR[it] = *(const int4*)((const unsigned short*)Av + aoff);  \
              }                                                               \
          }                                                                   \
          _Pragma("unroll")                                                   \
          for (int it = 0; it < PB; ++it) {                                   \
              const int c  = pw * PB + it;                                    \
              const int jg = jj ^ lr ^ (c & 7);                               \
              bR[it] = *(const int4*)(Bt +                                    \
                  (size_t)(colBase + c * 8 + lr) * KTOT + kk + jg * 8);       \
          } }

#define PC3_STORE(B_)                                                         \
        { unsigned short* As_ = As + (B_) * ASZ;                              \
          unsigned short* Bs_ = Bs + (B_) * BSZ;                              \
          _Pragma("unroll")                                                   \
          for (int it = 0; it < PA; ++it) {                                   \
              int4 v;                                                         \
              if constexpr (A_F32) {                                          \
                  v.x = (uint32_t)f2b(aF[it][0].x) |                          \
                        ((uint32_t)f2b(aF[it][0].y) << 16);                   \
                  v.y = (uint32_t)f2b(aF[it][0].z) |                          \
                        ((uint32_t)f2b(aF[it][0].w) << 16);                   \
                  v.z = (uint32_t)f2b(aF[it][1].x) |                          \
                        ((uint32_t)f2b(aF[it][1].y) << 16);                   \
                  v.w = (uint32_t)f2b(aF[it][1].z) |                          \
                        ((uint32_t)f2b(aF[it][1].w) << 16);                   \
              } else {                                                        \
                  v = aR[it];                                                 \
              }                                                               \
              *(int4*)&As_[(pw * PA + it) * 512 + lane * 8] = v;              \
          }                                                                   \
          _Pragma("unroll")                                                   \
          for (int it = 0; it < PB; ++it)                                     \
              *(int4*)&Bs_[(pw * PB + it) * 512 + lane * 8] = bR[it]; }

        // prologue: stage tile 0; issue tile-1 loads (in flight across bar)
        PC3_LOAD(0)
        PC3_STORE(0)
        PC3_LOAD(1)
        __syncthreads();

        for (int t = 0; t < NT; ++t) {
            if (t + 1 < NT) PC3_STORE((t + 1) & 1)    // regs from last iter
            if (t + 2 < NT) PC3_LOAD(t + 2)           // in flight across bar
            __syncthreads();
        }
#undef PC3_LOAD
#undef PC3_STORE
    } else {
        // ================= CONSUMER =================
        const int wm = wave >> 1, wn = wave & 1;
        const int waveM = wm * (BM / 2), waveN = wn * (BN / 2);
        f32x16 acc[FI][FJ] = {};

        __syncthreads();                  // tile 0 staged

        for (int t = 0; t < NT; ++t) {
            const unsigned short* Ab = As + (t & 1) * ASZ;
            const unsigned short* Bb = Bs + (t & 1) * BSZ;
#pragma unroll
            for (int ks = 0; ks < 4; ++ks) {
                bf16x8 a_f[FI], b_f[FJ];
                const int g = ks * 2 + khalf;
#pragma unroll
                for (int i = 0; i < FI; ++i) {
                    const int r = waveM + i * 32 + m32;
                    const int key = (r & 7) ^ ((r >> 3) & 7);
                    a_f[i] = *(const bf16x8*)&Ab[r * BK + ((g ^ key) << 3)];
                }
#pragma unroll
                for (int j = 0; j < FJ; ++j) {
                    const int r = waveN + j * 32 + m32;
                    const int key = (r & 7) ^ ((r >> 3) & 7);
                    b_f[j] = *(const bf16x8*)&Bb[r * BK + ((g ^ key) << 3)];
                }
#pragma unroll
                for (int i = 0; i < FI; ++i)
#pragma unroll
                    for (int j = 0; j < FJ; ++j)
                        acc[i][j] = __builtin_amdgcn_mfma_f32_32x32x16_bf16(
                            a_f[i], b_f[j], acc[i][j], 0, 0, 0);
            }
            __syncthreads();
        }

        // epilogue: col=lane&31, row=(reg&3)+8*(reg>>2)+4*(lane>>5)
#pragma unroll
        for (int i = 0; i < FI; ++i) {
#pragma unroll
            for (int j = 0; j < FJ; ++j) {
                const int col = colBase + waveN + j * 32 + m32;
                const float bv = bias[col];
#pragma unroll
                for (int reg = 0; reg < 16; ++reg) {
                    const int row = rowBase + waveM + i * 32 +
                                    (reg & 3) + 8 * (reg >> 2) + 4 * khalf;
                    float z = acc[i][j][reg] + bv;
                    if (DO_GELU)
                        z = 0.5f * z * (1.f + erff(z * 0.70710678118654752f));
                    const size_t off = (size_t)row * Ncols + col;
                    if (C_F32) ((float*)Cv)[off] = z;
                    else       ((unsigned short*)Cv)[off] = f2b(z);
                }
            }
        }
    }
}

// ---------------------------------------------------------------------------
extern "C" void kernel_launch(void* const* d_in, const int* in_sizes, int n_in,
                              void* d_out, int out_size, void* d_ws, size_t ws_size,
                              hipStream_t stream) {
    const float* x      = (const float*)d_in[0];   // [4096,1024] fp32
    const float* fc1_c0 = (const float*)d_in[1];
    const float* fc1_c1 = (const float*)d_in[2];
    const float* fc1_c2 = (const float*)d_in[3];
    const float* fc1_b  = (const float*)d_in[4];
    const float* fc2_c0 = (const float*)d_in[5];
    const float* fc2_c1 = (const float*)d_in[6];
    const float* fc2_c2 = (const float*)d_in[7];
    const float* fc2_b  = (const float*)d_in[8];

    // T scratch lives in d_out (16 MB f32): T1 [0,2M), T2 [2,4M).
    // Safe: gemm2 is the only d_out consumer and overwrites every element.
    float* T1 = (float*)d_out;
    float* T2 = (float*)d_out + 524288;

    char* ws = (char*)d_ws;
    const bool big = ws_size >= (48ull << 20);

    // K0: both T tensors (4096 blocks: 2048 + 2048)
    build_T_both<<<4096, 256, 0, stream>>>(fc1_c1, fc1_c2, T1,
                                           fc2_c1, fc2_c2, T2);

    if (big) {
        // ws: W1 [0,8M), W2 [8,16M), h bf16 [16,48M)
        unsigned short* W1 = (unsigned short*)ws;
        unsigned short* W2 = (unsigned short*)(ws + (8u << 20));
        unsigned short* h  = (unsigned short*)(ws + (16u << 20));

        // K1: both weight matrices (3072 blocks: 2048 + 1024)
        build_W_both<<<3072, 256, 0, stream>>>(fc1_c0, T1, W1,
                                               fc2_c0, T2, W2);
        // K2: GEMM1 [4096,1024]x[1024,4096] + bias + GELU -> h (bf16)
        //     A = x (fp32, converted in producer at store time)
        gemm_pc3<128, 128, 1024, true, true, false>
            <<<dim3(32, 32), 512, 0, stream>>>(x, W1, fc1_b, h, 4096);
        // K3: GEMM2 [4096,4096]x[4096,1024] + bias -> d_out (f32)
        gemm_pc3<128, 64, 4096, false, false, true>
            <<<dim3(16, 32), 512, 0, stream>>>(h, W2, fc2_b, d_out, 1024);
    } else {
        // Fallback (ws >= 40 MB): W [0,8M) reused per layer, h [8,40M).
        unsigned short* W = (unsigned short*)ws;
        unsigned short* h = (unsigned short*)(ws + (8u << 20));

        build_W<8, 16, 8, 16, 16, 16><<<2048, 256, 0, stream>>>(fc1_c0, T1, W);
        gemm_pc3<128, 128, 1024, true, true, false>
            <<<dim3(32, 32), 512, 0, stream>>>(x, W, fc1_b, h, 4096);
        build_W<16, 16, 16, 8, 16, 8><<<1024, 256, 0, stream>>>(fc2_c0, T2, W);
        gemm_pc3<128, 64, 4096, false, false, true>
            <<<dim3(16, 32), 512, 0, stream>>>(h, W, fc2_b, d_out, 1024);
    }
}